// Round 4
// baseline (2793.554 us; speedup 1.0000x reference)
//
#include <hip/hip_runtime.h>

#define BT 1024   // batch
#define TT 512    // total timesteps

__device__ __forceinline__ float sig_(float x) { return 1.f / (1.f + __expf(-x)); }
__device__ __forceinline__ float th_(float x)  { return 1.f - 2.f / (1.f + __expf(2.f * x)); }

// ---------------------------------------------------------------------------
// gemm_pre v2 (unchanged this round — R2 fixes confirmed, out of top-5):
// 4-k float4 inner step, two staged K-halves, strided row ownership.
// ---------------------------------------------------------------------------
template <int KS, int KPAD, int KH, int N, bool XMODE>
__device__ __forceinline__ void gp_stage(
    const float* __restrict__ A, const float* __restrict__ W,
    float (&As)[128][KPAD], float (&Bs)[KPAD][64],
    int tid, int n0, int by, int t0, int k0)
{
    constexpr int NQH = KH / 4;
#pragma unroll
    for (int ii = tid; ii < 128 * NQH; ii += 256) {
        int r = ii / NQH, q = ii % NQH;
        const float* src;
        if (XMODE) {
            int b  = (by & 7) * 128 + r;
            int tl = by >> 3;
            src = A + ((size_t)b * TT + (t0 + tl)) * KS;
        } else {
            src = A + (size_t)(by * 128 + r) * KS;
        }
        float4 v = *(const float4*)(src + k0 + q * 4);
        As[r][q * 4 + 0] = v.x; As[r][q * 4 + 1] = v.y;
        As[r][q * 4 + 2] = v.z; As[r][q * 4 + 3] = v.w;
    }
#pragma unroll
    for (int ii = tid; ii < 64 * NQH; ii += 256) {
        int n = ii & 63, kq = ii >> 6;
        float4 v = make_float4(0.f, 0.f, 0.f, 0.f);
        if (n0 + n < N) v = *(const float4*)(W + (size_t)(n0 + n) * KS + k0 + kq * 4);
        Bs[kq * 4 + 0][n] = v.x; Bs[kq * 4 + 1][n] = v.y;
        Bs[kq * 4 + 2][n] = v.z; Bs[kq * 4 + 3][n] = v.w;
    }
}

template <int KPAD, int KH>
__device__ __forceinline__ void gp_compute(
    const float (&As)[128][KPAD], const float (&Bs)[KPAD][64],
    float (&acc)[8][4], int tx, int ty)
{
    for (int kk = 0; kk < KH; kk += 4) {
        float4 bv0 = *(const float4*)&Bs[kk + 0][tx * 4];
        float4 bv1 = *(const float4*)&Bs[kk + 1][tx * 4];
        float4 bv2 = *(const float4*)&Bs[kk + 2][tx * 4];
        float4 bv3 = *(const float4*)&Bs[kk + 3][tx * 4];
#pragma unroll
        for (int i = 0; i < 8; i++) {
            float4 av = *(const float4*)&As[ty + 16 * i][kk];
            acc[i][0] = fmaf(av.x, bv0.x, acc[i][0]);
            acc[i][0] = fmaf(av.y, bv1.x, acc[i][0]);
            acc[i][0] = fmaf(av.z, bv2.x, acc[i][0]);
            acc[i][0] = fmaf(av.w, bv3.x, acc[i][0]);
            acc[i][1] = fmaf(av.x, bv0.y, acc[i][1]);
            acc[i][1] = fmaf(av.y, bv1.y, acc[i][1]);
            acc[i][1] = fmaf(av.z, bv2.y, acc[i][1]);
            acc[i][1] = fmaf(av.w, bv3.y, acc[i][1]);
            acc[i][2] = fmaf(av.x, bv0.z, acc[i][2]);
            acc[i][2] = fmaf(av.y, bv1.z, acc[i][2]);
            acc[i][2] = fmaf(av.z, bv2.z, acc[i][2]);
            acc[i][2] = fmaf(av.w, bv3.z, acc[i][2]);
            acc[i][3] = fmaf(av.x, bv0.w, acc[i][3]);
            acc[i][3] = fmaf(av.y, bv1.w, acc[i][3]);
            acc[i][3] = fmaf(av.z, bv2.w, acc[i][3]);
            acc[i][3] = fmaf(av.w, bv3.w, acc[i][3]);
        }
    }
}

template <int KS, int KPAD, int KH0, int N, bool XMODE>
__global__ __launch_bounds__(256, 4) void gemm_pre(
    const float* __restrict__ A, const float* __restrict__ W,
    const float* __restrict__ bih, const float* __restrict__ bhh,
    float* __restrict__ out, int t0)
{
    constexpr int KH1 = KS - KH0;
    __shared__ __align__(16) float As[128][KPAD];
    __shared__ __align__(16) float Bs[KPAD][64];
    const int tid = threadIdx.x;
    const int n0 = blockIdx.x * 64;
    const int by = blockIdx.y;
    const int Rbase = by * 128;
    const int tx = tid & 15, ty = tid >> 4;

    float acc[8][4];
#pragma unroll
    for (int i = 0; i < 8; i++)
#pragma unroll
        for (int j = 0; j < 4; j++) acc[i][j] = 0.f;

    gp_stage<KS, KPAD, KH0, N, XMODE>(A, W, As, Bs, tid, n0, by, t0, 0);
    __syncthreads();
    gp_compute<KPAD, KH0>(As, Bs, acc, tx, ty);
    __syncthreads();
    gp_stage<KS, KPAD, KH1, N, XMODE>(A, W, As, Bs, tid, n0, by, t0, KH0);
    __syncthreads();
    gp_compute<KPAD, KH1>(As, Bs, acc, tx, ty);

    int n = n0 + tx * 4;
    if (n < N) {
        float4 bias;
        bias.x = bih[n] + bhh[n];         bias.y = bih[n + 1] + bhh[n + 1];
        bias.z = bih[n + 2] + bhh[n + 2]; bias.w = bih[n + 3] + bhh[n + 3];
#pragma unroll
        for (int i = 0; i < 8; i++) {
            size_t R = (size_t)Rbase + ty + 16 * i;
            float4 o;
            o.x = acc[i][0] + bias.x; o.y = acc[i][1] + bias.y;
            o.z = acc[i][2] + bias.z; o.w = acc[i][3] + bias.w;
            *(float4*)(out + R * N + n) = o;
        }
    }
}

// ---------------------------------------------------------------------------
// rec1 v5 = v4 with __launch_bounds__(512, 2).
// R3 THEORY: v4's (512,4) cap (128 VGPR) pushed the RA into the 64-reg
// bucket — but w[4][5] needs 80 floats, so it REMATERIALIZED the Whh loads
// inside the t-loop (no scratch: WRITE_SIZE == hseq bytes exactly).
// 500thr x 512WG x 64t x 320B = 5.2 GB L2 traffic / 118 µs = 44 TB/s >
// 34.5 TB/s L2 ceiling -> rec1 was L2-BW-bound on redundant weight reloads.
// (512,2) caps at 256 regs; v3 proved the RA keeps ~124 there. At <=128
// VGPR both WGs still co-reside (16 waves/CU, LDS 2x23.5KB), so occupancy
// is unchanged and weights become loop-invariant in registers.
// CONFIRMATION SIGNAL: VGPR_Count must rise to ~100-130.
// DO NOT use min-waves=1 (prior-session container failures).
// ---------------------------------------------------------------------------
__global__ __launch_bounds__(512, 2) void rec1(
    const float* __restrict__ pre,   // [Tc][1024][400]
    const float* __restrict__ Whh,   // [400][100]
    float* __restrict__ hseq,        // [Tc][1024][100]
    float* __restrict__ cst,         // [1024][100]
    int Tc, int first)
{
    __shared__ __align__(16) float hs[2][100];
    __shared__ __align__(16) float pres[2][800];
    __shared__ float gbuf[5 * 4 * 2 * 100];
    const int tid = threadIdx.x;
    const int b0 = blockIdx.x * 2;

    const bool comp = tid < 500;
    const int j  = tid % 100;
    const int kq = tid / 100;

    float4 w[4][5];
    if (comp) {
#pragma unroll
        for (int g = 0; g < 4; g++) {
            const float4* W4 = (const float4*)(Whh + (size_t)(g * 100 + j) * 100);
#pragma unroll
            for (int q = 0; q < 5; q++) w[g][q] = W4[kq * 5 + q];
        }
    }

    const bool upd = tid < 200;
    const int ub = tid / 100, uj = tid % 100;
    float c = 0.f;
    if (upd) {
        float h = 0.f;
        if (!first) {
            h = hseq[((size_t)(Tc - 1) * BT + b0 + ub) * 100 + uj];
            c = cst[(size_t)(b0 + ub) * 100 + uj];
        }
        hs[ub][uj] = h;
        ((float4*)pres[0])[tid] = ((const float4*)(pre + (size_t)b0 * 400))[tid];
    }
    __syncthreads();

    int cur = 0;
    for (int t = 0; t < Tc; t++) {
        int tn = (t + 1 < Tc) ? (t + 1) : t;
        float4 pf0;
        if (upd)
            pf0 = ((const float4*)(pre + (size_t)tn * BT * 400 + (size_t)b0 * 400))[tid];

        if (comp) {
            float acc[4][2];
#pragma unroll
            for (int g = 0; g < 4; g++) { acc[g][0] = 0.f; acc[g][1] = 0.f; }
            const float4* h0 = (const float4*)hs[0];
            const float4* h1 = (const float4*)hs[1];
#pragma unroll
            for (int q = 0; q < 5; q++) {
                int f = kq * 5 + q;
                float4 v0 = h0[f], v1 = h1[f];
#pragma unroll
                for (int g = 0; g < 4; g++) {
                    float4 wq = w[g][q];
                    acc[g][0] = fmaf(wq.x, v0.x, acc[g][0]);
                    acc[g][0] = fmaf(wq.y, v0.y, acc[g][0]);
                    acc[g][0] = fmaf(wq.z, v0.z, acc[g][0]);
                    acc[g][0] = fmaf(wq.w, v0.w, acc[g][0]);
                    acc[g][1] = fmaf(wq.x, v1.x, acc[g][1]);
                    acc[g][1] = fmaf(wq.y, v1.y, acc[g][1]);
                    acc[g][1] = fmaf(wq.z, v1.z, acc[g][1]);
                    acc[g][1] = fmaf(wq.w, v1.w, acc[g][1]);
                }
            }
#pragma unroll
            for (int g = 0; g < 4; g++) {
                gbuf[((kq * 4 + g) * 2 + 0) * 100 + j] = acc[g][0];
                gbuf[((kq * 4 + g) * 2 + 1) * 100 + j] = acc[g][1];
            }
        }
        __syncthreads();

        if (upd) {
            const float* pb = pres[cur];
            float s0 = 0.f, s1 = 0.f, s2 = 0.f, s3 = 0.f;
#pragma unroll
            for (int q = 0; q < 5; q++) {
                int base = q * 800;
                s0 += gbuf[base + (0 * 2 + ub) * 100 + uj];
                s1 += gbuf[base + (1 * 2 + ub) * 100 + uj];
                s2 += gbuf[base + (2 * 2 + ub) * 100 + uj];
                s3 += gbuf[base + (3 * 2 + ub) * 100 + uj];
            }
            float xi = s0 + pb[ub * 400 + uj];
            float xf = s1 + pb[ub * 400 + 100 + uj];
            float xg = s2 + pb[ub * 400 + 200 + uj];
            float xo = s3 + pb[ub * 400 + 300 + uj];
            float ii = sig_(xi), ff = sig_(xf), gg = th_(xg), oo = sig_(xo);
            c = ff * c + ii * gg;
            float h = oo * th_(c);
            hs[ub][uj] = h;
            hseq[((size_t)t * BT + b0 + ub) * 100 + uj] = h;
            ((float4*)pres[cur ^ 1])[tid] = pf0;
        }
        __syncthreads();
        cur ^= 1;
    }
    if (upd) cst[(size_t)(b0 + ub) * 100 + uj] = c;
}

// ---------------------------------------------------------------------------
// rec2 v4 (unchanged: w footprint ~55 regs fits its 64-bucket, no remat risk).
// ---------------------------------------------------------------------------
__global__ __launch_bounds__(256, 4) void rec2(
    const float* __restrict__ pre2,  // [Tc][1024][200]
    const float* __restrict__ Whh,   // [200][50]
    float* __restrict__ cst, float* __restrict__ hst,  // [1024][50]
    float* __restrict__ out,         // [1024][50]
    int Tc, int first)
{
    __shared__ __align__(16) float hs[2][50];
    __shared__ __align__(16) float pres[2][400];
    __shared__ float gbuf[5 * 4 * 2 * 50];
    const int tid = threadIdx.x;
    const int b0 = blockIdx.x * 2;

    const bool comp = tid < 250;
    const int j  = tid % 50;
    const int kq = tid / 50;

    float2 w[4][5];
    if (comp) {
#pragma unroll
        for (int g = 0; g < 4; g++) {
            const float2* W2 = (const float2*)(Whh + (size_t)(g * 50 + j) * 50);
#pragma unroll
            for (int q = 0; q < 5; q++) w[g][q] = W2[kq * 5 + q];
        }
    }

    const bool upd = tid < 100;
    const int ub = tid / 50, uj = tid % 50;
    float c = 0.f, hlast = 0.f;
    if (upd) {
        float h = 0.f;
        if (!first) {
            h = hst[(size_t)(b0 + ub) * 50 + uj];
            c = cst[(size_t)(b0 + ub) * 50 + uj];
        }
        hs[ub][uj] = h;
        hlast = h;
        ((float4*)pres[0])[tid] = ((const float4*)(pre2 + (size_t)b0 * 200))[tid];
    }
    __syncthreads();

    int cur = 0;
    for (int t = 0; t < Tc; t++) {
        int tn = (t + 1 < Tc) ? (t + 1) : t;
        float4 pf0;
        if (upd)
            pf0 = ((const float4*)(pre2 + (size_t)tn * BT * 200 + (size_t)b0 * 200))[tid];

        if (comp) {
            float acc[4][2];
#pragma unroll
            for (int g = 0; g < 4; g++) { acc[g][0] = 0.f; acc[g][1] = 0.f; }
            const float2* hA = (const float2*)hs[0];
            const float2* hB = (const float2*)hs[1];
#pragma unroll
            for (int q = 0; q < 5; q++) {
                int f = kq * 5 + q;
                float2 v0 = hA[f], v1 = hB[f];
#pragma unroll
                for (int g = 0; g < 4; g++) {
                    float2 wq = w[g][q];
                    acc[g][0] = fmaf(wq.x, v0.x, acc[g][0]);
                    acc[g][0] = fmaf(wq.y, v0.y, acc[g][0]);
                    acc[g][1] = fmaf(wq.x, v1.x, acc[g][1]);
                    acc[g][1] = fmaf(wq.y, v1.y, acc[g][1]);
                }
            }
#pragma unroll
            for (int g = 0; g < 4; g++) {
                gbuf[((kq * 4 + g) * 2 + 0) * 50 + j] = acc[g][0];
                gbuf[((kq * 4 + g) * 2 + 1) * 50 + j] = acc[g][1];
            }
        }
        __syncthreads();

        if (upd) {
            const float* pb = pres[cur];
            float s0 = 0.f, s1 = 0.f, s2 = 0.f, s3 = 0.f;
#pragma unroll
            for (int q = 0; q < 5; q++) {
                int base = q * 400;
                s0 += gbuf[base + (0 * 2 + ub) * 50 + uj];
                s1 += gbuf[base + (1 * 2 + ub) * 50 + uj];
                s2 += gbuf[base + (2 * 2 + ub) * 50 + uj];
                s3 += gbuf[base + (3 * 2 + ub) * 50 + uj];
            }
            float xi = s0 + pb[ub * 200 + uj];
            float xf = s1 + pb[ub * 200 + 50 + uj];
            float xg = s2 + pb[ub * 200 + 100 + uj];
            float xo = s3 + pb[ub * 200 + 150 + uj];
            float ii = sig_(xi), ff = sig_(xf), gg = th_(xg), oo = sig_(xo);
            c = ff * c + ii * gg;
            float h = oo * th_(c);
            hs[ub][uj] = h;
            hlast = h;
            ((float4*)pres[cur ^ 1])[tid] = pf0;
        }
        __syncthreads();
        cur ^= 1;
    }
    if (upd) {
        cst[(size_t)(b0 + ub) * 50 + uj] = c;
        hst[(size_t)(b0 + ub) * 50 + uj] = hlast;
        out[(size_t)(b0 + ub) * 50 + uj] = hlast;
    }
}

// ---------------------------------------------------------------------------
extern "C" void kernel_launch(void* const* d_in, const int* in_sizes, int n_in,
                              void* d_out, int out_size, void* d_ws, size_t ws_size,
                              hipStream_t stream)
{
    const float* x    = (const float*)d_in[0];
    const float* Wih1 = (const float*)d_in[1];
    const float* Whh1 = (const float*)d_in[2];
    const float* bih1 = (const float*)d_in[3];
    const float* bhh1 = (const float*)d_in[4];
    const float* Wih2 = (const float*)d_in[5];
    const float* Whh2 = (const float*)d_in[6];
    const float* bih2 = (const float*)d_in[7];
    const float* bhh2 = (const float*)d_in[8];
    float* out = (float*)d_out;
    float* ws  = (float*)d_ws;

    int Tc = 64;
    auto need = [](int tc) -> size_t {
        return ((size_t)tc * 1024 * (400 + 100 + 200) +
                (size_t)1024 * 100 + (size_t)1024 * 50 * 2) * sizeof(float);
    };
    while (Tc > 1 && need(Tc) > ws_size) Tc >>= 1;

    float* pre1 = ws;
    float* h1s  = pre1 + (size_t)Tc * 1024 * 400;
    float* pre2 = h1s  + (size_t)Tc * 1024 * 100;
    float* c1   = pre2 + (size_t)Tc * 1024 * 200;
    float* c2   = c1 + 1024 * 100;
    float* h2st = c2 + 1024 * 50;

    const int nch = TT / Tc;
    for (int ch = 0; ch < nch; ch++) {
        int t0 = ch * Tc;
        // K=80: halves 40+40, LDS 30.7KB -> 4 WGs/CU
        gemm_pre<80, 40, 40, 400, true ><<<dim3(7, Tc * 8), 256, 0, stream>>>(
            x, Wih1, bih1, bhh1, pre1, t0);
        rec1<<<dim3(512), dim3(512), 0, stream>>>(pre1, Whh1, h1s, c1, Tc, ch == 0 ? 1 : 0);
        // K=100: halves 52+48, LDS 39.9KB -> 4 WGs/CU
        gemm_pre<100, 52, 52, 200, false><<<dim3(4, Tc * 8), 256, 0, stream>>>(
            h1s, Wih2, bih2, bhh2, pre2, 0);
        rec2<<<dim3(512), dim3(256), 0, stream>>>(pre2, Whh2, c2, h2st, out, Tc, ch == 0 ? 1 : 0);
    }
}

// Round 5
// 2693.075 us; speedup vs baseline: 1.0373x; 1.0373x over previous
//
#include <hip/hip_runtime.h>

#define BT 1024   // batch
#define TT 512    // total timesteps

__device__ __forceinline__ float sig_(float x) { return 1.f / (1.f + __expf(-x)); }
__device__ __forceinline__ float th_(float x)  { return 1.f - 2.f / (1.f + __expf(2.f * x)); }

// Pin a loaded value into VGPRs: an asm output cannot be rematerialized,
// so the weight loads can no longer be sunk into the t-loop (R3 lesson:
// the RA remats guarded loop-invariant loads at ANY register budget).
#define PIN4(v) asm volatile("" : "+v"((v).x), "+v"((v).y), "+v"((v).z), "+v"((v).w))
#define PIN2(v) asm volatile("" : "+v"((v).x), "+v"((v).y))

// ---------------------------------------------------------------------------
// gemm_pre v2 (unchanged — R2 fixes confirmed, out of top-5):
// 4-k float4 inner step, two staged K-halves, strided row ownership.
// ---------------------------------------------------------------------------
template <int KS, int KPAD, int KH, int N, bool XMODE>
__device__ __forceinline__ void gp_stage(
    const float* __restrict__ A, const float* __restrict__ W,
    float (&As)[128][KPAD], float (&Bs)[KPAD][64],
    int tid, int n0, int by, int t0, int k0)
{
    constexpr int NQH = KH / 4;
#pragma unroll
    for (int ii = tid; ii < 128 * NQH; ii += 256) {
        int r = ii / NQH, q = ii % NQH;
        const float* src;
        if (XMODE) {
            int b  = (by & 7) * 128 + r;
            int tl = by >> 3;
            src = A + ((size_t)b * TT + (t0 + tl)) * KS;
        } else {
            src = A + (size_t)(by * 128 + r) * KS;
        }
        float4 v = *(const float4*)(src + k0 + q * 4);
        As[r][q * 4 + 0] = v.x; As[r][q * 4 + 1] = v.y;
        As[r][q * 4 + 2] = v.z; As[r][q * 4 + 3] = v.w;
    }
#pragma unroll
    for (int ii = tid; ii < 64 * NQH; ii += 256) {
        int n = ii & 63, kq = ii >> 6;
        float4 v = make_float4(0.f, 0.f, 0.f, 0.f);
        if (n0 + n < N) v = *(const float4*)(W + (size_t)(n0 + n) * KS + k0 + kq * 4);
        Bs[kq * 4 + 0][n] = v.x; Bs[kq * 4 + 1][n] = v.y;
        Bs[kq * 4 + 2][n] = v.z; Bs[kq * 4 + 3][n] = v.w;
    }
}

template <int KPAD, int KH>
__device__ __forceinline__ void gp_compute(
    const float (&As)[128][KPAD], const float (&Bs)[KPAD][64],
    float (&acc)[8][4], int tx, int ty)
{
    for (int kk = 0; kk < KH; kk += 4) {
        float4 bv0 = *(const float4*)&Bs[kk + 0][tx * 4];
        float4 bv1 = *(const float4*)&Bs[kk + 1][tx * 4];
        float4 bv2 = *(const float4*)&Bs[kk + 2][tx * 4];
        float4 bv3 = *(const float4*)&Bs[kk + 3][tx * 4];
#pragma unroll
        for (int i = 0; i < 8; i++) {
            float4 av = *(const float4*)&As[ty + 16 * i][kk];
            acc[i][0] = fmaf(av.x, bv0.x, acc[i][0]);
            acc[i][0] = fmaf(av.y, bv1.x, acc[i][0]);
            acc[i][0] = fmaf(av.z, bv2.x, acc[i][0]);
            acc[i][0] = fmaf(av.w, bv3.x, acc[i][0]);
            acc[i][1] = fmaf(av.x, bv0.y, acc[i][1]);
            acc[i][1] = fmaf(av.y, bv1.y, acc[i][1]);
            acc[i][1] = fmaf(av.z, bv2.y, acc[i][1]);
            acc[i][1] = fmaf(av.w, bv3.y, acc[i][1]);
            acc[i][2] = fmaf(av.x, bv0.z, acc[i][2]);
            acc[i][2] = fmaf(av.y, bv1.z, acc[i][2]);
            acc[i][2] = fmaf(av.z, bv2.z, acc[i][2]);
            acc[i][2] = fmaf(av.w, bv3.z, acc[i][2]);
            acc[i][3] = fmaf(av.x, bv0.w, acc[i][3]);
            acc[i][3] = fmaf(av.y, bv1.w, acc[i][3]);
            acc[i][3] = fmaf(av.z, bv2.w, acc[i][3]);
            acc[i][3] = fmaf(av.w, bv3.w, acc[i][3]);
        }
    }
}

template <int KS, int KPAD, int KH0, int N, bool XMODE>
__global__ __launch_bounds__(256, 4) void gemm_pre(
    const float* __restrict__ A, const float* __restrict__ W,
    const float* __restrict__ bih, const float* __restrict__ bhh,
    float* __restrict__ out, int t0)
{
    constexpr int KH1 = KS - KH0;
    __shared__ __align__(16) float As[128][KPAD];
    __shared__ __align__(16) float Bs[KPAD][64];
    const int tid = threadIdx.x;
    const int n0 = blockIdx.x * 64;
    const int by = blockIdx.y;
    const int Rbase = by * 128;
    const int tx = tid & 15, ty = tid >> 4;

    float acc[8][4];
#pragma unroll
    for (int i = 0; i < 8; i++)
#pragma unroll
        for (int j = 0; j < 4; j++) acc[i][j] = 0.f;

    gp_stage<KS, KPAD, KH0, N, XMODE>(A, W, As, Bs, tid, n0, by, t0, 0);
    __syncthreads();
    gp_compute<KPAD, KH0>(As, Bs, acc, tx, ty);
    __syncthreads();
    gp_stage<KS, KPAD, KH1, N, XMODE>(A, W, As, Bs, tid, n0, by, t0, KH0);
    __syncthreads();
    gp_compute<KPAD, KH1>(As, Bs, acc, tx, ty);

    int n = n0 + tx * 4;
    if (n < N) {
        float4 bias;
        bias.x = bih[n] + bhh[n];         bias.y = bih[n + 1] + bhh[n + 1];
        bias.z = bih[n + 2] + bhh[n + 2]; bias.w = bih[n + 3] + bhh[n + 3];
#pragma unroll
        for (int i = 0; i < 8; i++) {
            size_t R = (size_t)Rbase + ty + 16 * i;
            float4 o;
            o.x = acc[i][0] + bias.x; o.y = acc[i][1] + bias.y;
            o.z = acc[i][2] + bias.z; o.w = acc[i][3] + bias.w;
            *(float4*)(out + R * N + n) = o;
        }
    }
}

// ---------------------------------------------------------------------------
// rec1 v6 = R1's (512,4) kernel + asm-pinned weights.
// R4 THEORY: R1@118µs was L2-BW-bound on remat'd Whh loads (320KB/CU/t ~
// 72 B/cyc > ~56 B/cyc L2 ceiling). R3 proved launch-bounds can't stop the
// remat (VGPR stayed 72 at a 256 budget) and (512,2) loses occupancy.
// So: (512,4) for occupancy + PIN4 to force the 80 weight regs resident.
// Worst-case thread (upd & comp) ≈ 118 live regs < 128 cap.
// CONFIRMATION: VGPR_Count ~110-128 and WRITE_SIZE stays 26MB (no spill).
// DO NOT use min-waves=1 (prior-session container failures).
// ---------------------------------------------------------------------------
__global__ __launch_bounds__(512, 4) void rec1(
    const float* __restrict__ pre,   // [Tc][1024][400]
    const float* __restrict__ Whh,   // [400][100]
    float* __restrict__ hseq,        // [Tc][1024][100]
    float* __restrict__ cst,         // [1024][100]
    int Tc, int first)
{
    __shared__ __align__(16) float hs[2][100];
    __shared__ __align__(16) float pres[2][800];
    __shared__ float gbuf[5 * 4 * 2 * 100];
    const int tid = threadIdx.x;
    const int b0 = blockIdx.x * 2;

    const bool comp = tid < 500;
    const int j  = tid % 100;
    const int kq = tid / 100;

    float4 w[4][5];
    if (comp) {
#pragma unroll
        for (int g = 0; g < 4; g++) {
            const float4* W4 = (const float4*)(Whh + (size_t)(g * 100 + j) * 100);
#pragma unroll
            for (int q = 0; q < 5; q++) w[g][q] = W4[kq * 5 + q];
        }
#pragma unroll
        for (int g = 0; g < 4; g++)
#pragma unroll
            for (int q = 0; q < 5; q++) PIN4(w[g][q]);
    }

    const bool upd = tid < 200;
    const int ub = tid / 100, uj = tid % 100;
    float c = 0.f;
    if (upd) {
        float h = 0.f;
        if (!first) {
            h = hseq[((size_t)(Tc - 1) * BT + b0 + ub) * 100 + uj];
            c = cst[(size_t)(b0 + ub) * 100 + uj];
        }
        hs[ub][uj] = h;
        ((float4*)pres[0])[tid] = ((const float4*)(pre + (size_t)b0 * 400))[tid];
    }
    __syncthreads();

    int cur = 0;
    for (int t = 0; t < Tc; t++) {
        int tn = (t + 1 < Tc) ? (t + 1) : t;
        float4 pf0;
        if (upd)
            pf0 = ((const float4*)(pre + (size_t)tn * BT * 400 + (size_t)b0 * 400))[tid];

        if (comp) {
            float acc[4][2];
#pragma unroll
            for (int g = 0; g < 4; g++) { acc[g][0] = 0.f; acc[g][1] = 0.f; }
            const float4* h0 = (const float4*)hs[0];
            const float4* h1 = (const float4*)hs[1];
#pragma unroll
            for (int q = 0; q < 5; q++) {
                int f = kq * 5 + q;
                float4 v0 = h0[f], v1 = h1[f];
#pragma unroll
                for (int g = 0; g < 4; g++) {
                    float4 wq = w[g][q];
                    acc[g][0] = fmaf(wq.x, v0.x, acc[g][0]);
                    acc[g][0] = fmaf(wq.y, v0.y, acc[g][0]);
                    acc[g][0] = fmaf(wq.z, v0.z, acc[g][0]);
                    acc[g][0] = fmaf(wq.w, v0.w, acc[g][0]);
                    acc[g][1] = fmaf(wq.x, v1.x, acc[g][1]);
                    acc[g][1] = fmaf(wq.y, v1.y, acc[g][1]);
                    acc[g][1] = fmaf(wq.z, v1.z, acc[g][1]);
                    acc[g][1] = fmaf(wq.w, v1.w, acc[g][1]);
                }
            }
#pragma unroll
            for (int g = 0; g < 4; g++) {
                gbuf[((kq * 4 + g) * 2 + 0) * 100 + j] = acc[g][0];
                gbuf[((kq * 4 + g) * 2 + 1) * 100 + j] = acc[g][1];
            }
        }
        __syncthreads();

        if (upd) {
            const float* pb = pres[cur];
            float s0 = 0.f, s1 = 0.f, s2 = 0.f, s3 = 0.f;
#pragma unroll
            for (int q = 0; q < 5; q++) {
                int base = q * 800;
                s0 += gbuf[base + (0 * 2 + ub) * 100 + uj];
                s1 += gbuf[base + (1 * 2 + ub) * 100 + uj];
                s2 += gbuf[base + (2 * 2 + ub) * 100 + uj];
                s3 += gbuf[base + (3 * 2 + ub) * 100 + uj];
            }
            float xi = s0 + pb[ub * 400 + uj];
            float xf = s1 + pb[ub * 400 + 100 + uj];
            float xg = s2 + pb[ub * 400 + 200 + uj];
            float xo = s3 + pb[ub * 400 + 300 + uj];
            float ii = sig_(xi), ff = sig_(xf), gg = th_(xg), oo = sig_(xo);
            c = ff * c + ii * gg;
            float h = oo * th_(c);
            hs[ub][uj] = h;
            hseq[((size_t)t * BT + b0 + ub) * 100 + uj] = h;
            ((float4*)pres[cur ^ 1])[tid] = pf0;
        }
        __syncthreads();
        cur ^= 1;
    }
    if (upd) cst[(size_t)(b0 + ub) * 100 + uj] = c;
}

// ---------------------------------------------------------------------------
// rec2 v5 = v4 + pinned weights (40 regs, ample slack under the 128 cap).
// ---------------------------------------------------------------------------
__global__ __launch_bounds__(256, 4) void rec2(
    const float* __restrict__ pre2,  // [Tc][1024][200]
    const float* __restrict__ Whh,   // [200][50]
    float* __restrict__ cst, float* __restrict__ hst,  // [1024][50]
    float* __restrict__ out,         // [1024][50]
    int Tc, int first)
{
    __shared__ __align__(16) float hs[2][50];
    __shared__ __align__(16) float pres[2][400];
    __shared__ float gbuf[5 * 4 * 2 * 50];
    const int tid = threadIdx.x;
    const int b0 = blockIdx.x * 2;

    const bool comp = tid < 250;
    const int j  = tid % 50;
    const int kq = tid / 50;

    float2 w[4][5];
    if (comp) {
#pragma unroll
        for (int g = 0; g < 4; g++) {
            const float2* W2 = (const float2*)(Whh + (size_t)(g * 50 + j) * 50);
#pragma unroll
            for (int q = 0; q < 5; q++) w[g][q] = W2[kq * 5 + q];
        }
#pragma unroll
        for (int g = 0; g < 4; g++)
#pragma unroll
            for (int q = 0; q < 5; q++) PIN2(w[g][q]);
    }

    const bool upd = tid < 100;
    const int ub = tid / 50, uj = tid % 50;
    float c = 0.f, hlast = 0.f;
    if (upd) {
        float h = 0.f;
        if (!first) {
            h = hst[(size_t)(b0 + ub) * 50 + uj];
            c = cst[(size_t)(b0 + ub) * 50 + uj];
        }
        hs[ub][uj] = h;
        hlast = h;
        ((float4*)pres[0])[tid] = ((const float4*)(pre2 + (size_t)b0 * 200))[tid];
    }
    __syncthreads();

    int cur = 0;
    for (int t = 0; t < Tc; t++) {
        int tn = (t + 1 < Tc) ? (t + 1) : t;
        float4 pf0;
        if (upd)
            pf0 = ((const float4*)(pre2 + (size_t)tn * BT * 200 + (size_t)b0 * 200))[tid];

        if (comp) {
            float acc[4][2];
#pragma unroll
            for (int g = 0; g < 4; g++) { acc[g][0] = 0.f; acc[g][1] = 0.f; }
            const float2* hA = (const float2*)hs[0];
            const float2* hB = (const float2*)hs[1];
#pragma unroll
            for (int q = 0; q < 5; q++) {
                int f = kq * 5 + q;
                float2 v0 = hA[f], v1 = hB[f];
#pragma unroll
                for (int g = 0; g < 4; g++) {
                    float2 wq = w[g][q];
                    acc[g][0] = fmaf(wq.x, v0.x, acc[g][0]);
                    acc[g][0] = fmaf(wq.y, v0.y, acc[g][0]);
                    acc[g][1] = fmaf(wq.x, v1.x, acc[g][1]);
                    acc[g][1] = fmaf(wq.y, v1.y, acc[g][1]);
                }
            }
#pragma unroll
            for (int g = 0; g < 4; g++) {
                gbuf[((kq * 4 + g) * 2 + 0) * 50 + j] = acc[g][0];
                gbuf[((kq * 4 + g) * 2 + 1) * 50 + j] = acc[g][1];
            }
        }
        __syncthreads();

        if (upd) {
            const float* pb = pres[cur];
            float s0 = 0.f, s1 = 0.f, s2 = 0.f, s3 = 0.f;
#pragma unroll
            for (int q = 0; q < 5; q++) {
                int base = q * 400;
                s0 += gbuf[base + (0 * 2 + ub) * 50 + uj];
                s1 += gbuf[base + (1 * 2 + ub) * 50 + uj];
                s2 += gbuf[base + (2 * 2 + ub) * 50 + uj];
                s3 += gbuf[base + (3 * 2 + ub) * 50 + uj];
            }
            float xi = s0 + pb[ub * 200 + uj];
            float xf = s1 + pb[ub * 200 + 50 + uj];
            float xg = s2 + pb[ub * 200 + 100 + uj];
            float xo = s3 + pb[ub * 200 + 150 + uj];
            float ii = sig_(xi), ff = sig_(xf), gg = th_(xg), oo = sig_(xo);
            c = ff * c + ii * gg;
            float h = oo * th_(c);
            hs[ub][uj] = h;
            hlast = h;
            ((float4*)pres[cur ^ 1])[tid] = pf0;
        }
        __syncthreads();
        cur ^= 1;
    }
    if (upd) {
        cst[(size_t)(b0 + ub) * 50 + uj] = c;
        hst[(size_t)(b0 + ub) * 50 + uj] = hlast;
        out[(size_t)(b0 + ub) * 50 + uj] = hlast;
    }
}

// ---------------------------------------------------------------------------
extern "C" void kernel_launch(void* const* d_in, const int* in_sizes, int n_in,
                              void* d_out, int out_size, void* d_ws, size_t ws_size,
                              hipStream_t stream)
{
    const float* x    = (const float*)d_in[0];
    const float* Wih1 = (const float*)d_in[1];
    const float* Whh1 = (const float*)d_in[2];
    const float* bih1 = (const float*)d_in[3];
    const float* bhh1 = (const float*)d_in[4];
    const float* Wih2 = (const float*)d_in[5];
    const float* Whh2 = (const float*)d_in[6];
    const float* bih2 = (const float*)d_in[7];
    const float* bhh2 = (const float*)d_in[8];
    float* out = (float*)d_out;
    float* ws  = (float*)d_ws;

    int Tc = 64;
    auto need = [](int tc) -> size_t {
        return ((size_t)tc * 1024 * (400 + 100 + 200) +
                (size_t)1024 * 100 + (size_t)1024 * 50 * 2) * sizeof(float);
    };
    while (Tc > 1 && need(Tc) > ws_size) Tc >>= 1;

    float* pre1 = ws;
    float* h1s  = pre1 + (size_t)Tc * 1024 * 400;
    float* pre2 = h1s  + (size_t)Tc * 1024 * 100;
    float* c1   = pre2 + (size_t)Tc * 1024 * 200;
    float* c2   = c1 + 1024 * 100;
    float* h2st = c2 + 1024 * 50;

    const int nch = TT / Tc;
    for (int ch = 0; ch < nch; ch++) {
        int t0 = ch * Tc;
        // K=80: halves 40+40, LDS 30.7KB -> 4 WGs/CU
        gemm_pre<80, 40, 40, 400, true ><<<dim3(7, Tc * 8), 256, 0, stream>>>(
            x, Wih1, bih1, bhh1, pre1, t0);
        rec1<<<dim3(512), dim3(512), 0, stream>>>(pre1, Whh1, h1s, c1, Tc, ch == 0 ? 1 : 0);
        // K=100: halves 52+48, LDS 39.9KB -> 4 WGs/CU
        gemm_pre<100, 52, 52, 200, false><<<dim3(4, Tc * 8), 256, 0, stream>>>(
            h1s, Wih2, bih2, bhh2, pre2, 0);
        rec2<<<dim3(512), dim3(256), 0, stream>>>(pre2, Whh2, c2, h2st, out, Tc, ch == 0 ? 1 : 0);
    }
}

// Round 6
// 2614.688 us; speedup vs baseline: 1.0684x; 1.0300x over previous
//
#include <hip/hip_runtime.h>

#define BT 1024   // batch
#define TT 512    // total timesteps

__device__ __forceinline__ float sig_(float x) { return 1.f / (1.f + __expf(-x)); }
__device__ __forceinline__ float th_(float x)  { return 1.f - 2.f / (1.f + __expf(2.f * x)); }

// ---------------------------------------------------------------------------
// gemm_pre v3. R5 THEORY: v2's compute loop was DS-pipe-bound (12 b128 per
// 32 fmaf = 144 DS cyc vs 64 VALU cyc -> VALUBusy 31%). 8x8 micro-tile:
// per 4-k step 16 b128 vs 256 fmaf (512 VALU vs ~230 DS cyc) -> VALU-bound.
// Col-tile 128 (two f4 per thread), row ownership stays strided (ty+16i,
// conflict-free As reads: banks {8ty}/{20ty} distinct). Bs reads are 4-way
// (16 tx x stride 32B) - accepted, ~1.3x on 8 of 16 DS instrs.
// LDS As+Bs = 41KB (K=80) / 53KB (K=100) -> 3 WGs/CU; (256,3) caps VGPR
// ~168 (acc 64 + bv 32 + misc ~110 live). min-waves=1 still forbidden.
// ---------------------------------------------------------------------------
template <int KS, int KPAD, int KH, int N, bool XMODE>
__device__ __forceinline__ void gp_stage(
    const float* __restrict__ A, const float* __restrict__ W,
    float (&As)[128][KPAD], float (&Bs)[KPAD][128],
    int tid, int n0, int by, int t0, int k0)
{
    constexpr int NQH = KH / 4;
#pragma unroll
    for (int ii = tid; ii < 128 * NQH; ii += 256) {
        int r = ii / NQH, q = ii % NQH;
        const float* src;
        if (XMODE) {
            int b  = (by & 7) * 128 + r;
            int tl = by >> 3;
            src = A + ((size_t)b * TT + (t0 + tl)) * KS;
        } else {
            src = A + (size_t)(by * 128 + r) * KS;
        }
        *(float4*)&As[r][q * 4] = *(const float4*)(src + k0 + q * 4);
    }
#pragma unroll
    for (int ii = tid; ii < 128 * NQH; ii += 256) {
        int n = ii & 127, kq = ii >> 7;
        float4 v = make_float4(0.f, 0.f, 0.f, 0.f);
        if (n0 + n < N) v = *(const float4*)(W + (size_t)(n0 + n) * KS + k0 + kq * 4);
        Bs[kq * 4 + 0][n] = v.x; Bs[kq * 4 + 1][n] = v.y;
        Bs[kq * 4 + 2][n] = v.z; Bs[kq * 4 + 3][n] = v.w;
    }
}

template <int KPAD, int KH>
__device__ __forceinline__ void gp_compute(
    const float (&As)[128][KPAD], const float (&Bs)[KPAD][128],
    float (&acc)[8][8], int tx, int ty)
{
    for (int kk = 0; kk < KH; kk += 4) {
        float4 bv[4][2];
#pragma unroll
        for (int r = 0; r < 4; r++) {
            bv[r][0] = *(const float4*)&Bs[kk + r][tx * 8];
            bv[r][1] = *(const float4*)&Bs[kk + r][tx * 8 + 4];
        }
#pragma unroll
        for (int i = 0; i < 8; i++) {
            float4 av = *(const float4*)&As[ty + 16 * i][kk];
#pragma unroll
            for (int s = 0; s < 2; s++) {
                acc[i][s*4+0] = fmaf(av.x, bv[0][s].x, acc[i][s*4+0]);
                acc[i][s*4+0] = fmaf(av.y, bv[1][s].x, acc[i][s*4+0]);
                acc[i][s*4+0] = fmaf(av.z, bv[2][s].x, acc[i][s*4+0]);
                acc[i][s*4+0] = fmaf(av.w, bv[3][s].x, acc[i][s*4+0]);
                acc[i][s*4+1] = fmaf(av.x, bv[0][s].y, acc[i][s*4+1]);
                acc[i][s*4+1] = fmaf(av.y, bv[1][s].y, acc[i][s*4+1]);
                acc[i][s*4+1] = fmaf(av.z, bv[2][s].y, acc[i][s*4+1]);
                acc[i][s*4+1] = fmaf(av.w, bv[3][s].y, acc[i][s*4+1]);
                acc[i][s*4+2] = fmaf(av.x, bv[0][s].z, acc[i][s*4+2]);
                acc[i][s*4+2] = fmaf(av.y, bv[1][s].z, acc[i][s*4+2]);
                acc[i][s*4+2] = fmaf(av.z, bv[2][s].z, acc[i][s*4+2]);
                acc[i][s*4+2] = fmaf(av.w, bv[3][s].z, acc[i][s*4+2]);
                acc[i][s*4+3] = fmaf(av.x, bv[0][s].w, acc[i][s*4+3]);
                acc[i][s*4+3] = fmaf(av.y, bv[1][s].w, acc[i][s*4+3]);
                acc[i][s*4+3] = fmaf(av.z, bv[2][s].w, acc[i][s*4+3]);
                acc[i][s*4+3] = fmaf(av.w, bv[3][s].w, acc[i][s*4+3]);
            }
        }
    }
}

template <int KS, int KPAD, int KH0, int N, bool XMODE>
__global__ __launch_bounds__(256, 3) void gemm_pre(
    const float* __restrict__ A, const float* __restrict__ W,
    const float* __restrict__ bih, const float* __restrict__ bhh,
    float* __restrict__ out, int t0)
{
    constexpr int KH1 = KS - KH0;
    __shared__ __align__(16) float As[128][KPAD];
    __shared__ __align__(16) float Bs[KPAD][128];
    const int tid = threadIdx.x;
    const int n0 = blockIdx.x * 128;
    const int by = blockIdx.y;
    const int Rbase = by * 128;
    const int tx = tid & 15, ty = tid >> 4;

    float acc[8][8];
#pragma unroll
    for (int i = 0; i < 8; i++)
#pragma unroll
        for (int j = 0; j < 8; j++) acc[i][j] = 0.f;

    gp_stage<KS, KPAD, KH0, N, XMODE>(A, W, As, Bs, tid, n0, by, t0, 0);
    __syncthreads();
    gp_compute<KPAD, KH0>(As, Bs, acc, tx, ty);
    __syncthreads();
    gp_stage<KS, KPAD, KH1, N, XMODE>(A, W, As, Bs, tid, n0, by, t0, KH0);
    __syncthreads();
    gp_compute<KPAD, KH1>(As, Bs, acc, tx, ty);

#pragma unroll
    for (int s = 0; s < 2; s++) {
        int n = n0 + tx * 8 + s * 4;
        if (n < N) {
            float4 bias;
            bias.x = bih[n] + bhh[n];         bias.y = bih[n + 1] + bhh[n + 1];
            bias.z = bih[n + 2] + bhh[n + 2]; bias.w = bih[n + 3] + bhh[n + 3];
#pragma unroll
            for (int i = 0; i < 8; i++) {
                size_t R = (size_t)Rbase + ty + 16 * i;
                float4 o;
                o.x = acc[i][s*4+0] + bias.x; o.y = acc[i][s*4+1] + bias.y;
                o.z = acc[i][s*4+2] + bias.z; o.w = acc[i][s*4+3] + bias.w;
                *(float4*)(out + R * N + n) = o;
            }
        }
    }
}

// ---------------------------------------------------------------------------
// rec1 v7 = R1's v4 (512,4), NO pin (R4/R5: pin -> AGPR shuffle, no gain;
// weights live in AGPR/remat either way — structural plateau), plus cheap
// VALU trims: t-loop unrolled x2 (static pres indices kill the cur-flip
// address VALU), accumulators mul-initialized (saves 8 v_movs/t).
// ---------------------------------------------------------------------------
__global__ __launch_bounds__(512, 4) void rec1(
    const float* __restrict__ pre,   // [Tc][1024][400]
    const float* __restrict__ Whh,   // [400][100]
    float* __restrict__ hseq,        // [Tc][1024][100]
    float* __restrict__ cst,         // [1024][100]
    int Tc, int first)
{
    __shared__ __align__(16) float hs[2][100];
    __shared__ __align__(16) float pres[2][800];
    __shared__ float gbuf[5 * 4 * 2 * 100];
    const int tid = threadIdx.x;
    const int b0 = blockIdx.x * 2;

    const bool comp = tid < 500;
    const int j  = tid % 100;
    const int kq = tid / 100;

    float4 w[4][5];
    if (comp) {
#pragma unroll
        for (int g = 0; g < 4; g++) {
            const float4* W4 = (const float4*)(Whh + (size_t)(g * 100 + j) * 100);
#pragma unroll
            for (int q = 0; q < 5; q++) w[g][q] = W4[kq * 5 + q];
        }
    }

    const bool upd = tid < 200;
    const int ub = tid / 100, uj = tid % 100;
    float c = 0.f;
    if (upd) {
        float h = 0.f;
        if (!first) {
            h = hseq[((size_t)(Tc - 1) * BT + b0 + ub) * 100 + uj];
            c = cst[(size_t)(b0 + ub) * 100 + uj];
        }
        hs[ub][uj] = h;
        ((float4*)pres[0])[tid] = ((const float4*)(pre + (size_t)b0 * 400))[tid];
    }
    __syncthreads();

#define REC1_BODY(T_, PCUR, PNXT)                                              \
    {                                                                          \
        int tn = ((T_) + 1 < Tc) ? ((T_) + 1) : (T_);                          \
        float4 pf0;                                                            \
        if (upd)                                                               \
            pf0 = ((const float4*)(pre + (size_t)tn * BT * 400 +               \
                                   (size_t)b0 * 400))[tid];                    \
        if (comp) {                                                            \
            float acc[4][2];                                                   \
            const float4* h0 = (const float4*)hs[0];                           \
            const float4* h1 = (const float4*)hs[1];                           \
            {   /* q = 0: mul-init */                                          \
                int f = kq * 5;                                                \
                float4 v0 = h0[f], v1 = h1[f];                                 \
                _Pragma("unroll")                                              \
                for (int g = 0; g < 4; g++) {                                  \
                    float4 wq = w[g][0];                                       \
                    float a0 = wq.x * v0.x;                                    \
                    a0 = fmaf(wq.y, v0.y, a0);                                 \
                    a0 = fmaf(wq.z, v0.z, a0);                                 \
                    a0 = fmaf(wq.w, v0.w, a0);                                 \
                    float a1 = wq.x * v1.x;                                    \
                    a1 = fmaf(wq.y, v1.y, a1);                                 \
                    a1 = fmaf(wq.z, v1.z, a1);                                 \
                    a1 = fmaf(wq.w, v1.w, a1);                                 \
                    acc[g][0] = a0; acc[g][1] = a1;                            \
                }                                                              \
            }                                                                  \
            _Pragma("unroll")                                                  \
            for (int q = 1; q < 5; q++) {                                      \
                int f = kq * 5 + q;                                            \
                float4 v0 = h0[f], v1 = h1[f];                                 \
                _Pragma("unroll")                                              \
                for (int g = 0; g < 4; g++) {                                  \
                    float4 wq = w[g][q];                                       \
                    acc[g][0] = fmaf(wq.x, v0.x, acc[g][0]);                   \
                    acc[g][0] = fmaf(wq.y, v0.y, acc[g][0]);                   \
                    acc[g][0] = fmaf(wq.z, v0.z, acc[g][0]);                   \
                    acc[g][0] = fmaf(wq.w, v0.w, acc[g][0]);                   \
                    acc[g][1] = fmaf(wq.x, v1.x, acc[g][1]);                   \
                    acc[g][1] = fmaf(wq.y, v1.y, acc[g][1]);                   \
                    acc[g][1] = fmaf(wq.z, v1.z, acc[g][1]);                   \
                    acc[g][1] = fmaf(wq.w, v1.w, acc[g][1]);                   \
                }                                                              \
            }                                                                  \
            _Pragma("unroll")                                                  \
            for (int g = 0; g < 4; g++) {                                      \
                gbuf[((kq * 4 + g) * 2 + 0) * 100 + j] = acc[g][0];            \
                gbuf[((kq * 4 + g) * 2 + 1) * 100 + j] = acc[g][1];            \
            }                                                                  \
        }                                                                      \
        __syncthreads();                                                       \
        if (upd) {                                                             \
            const float* pb = (PCUR);                                          \
            float s0 = 0.f, s1 = 0.f, s2 = 0.f, s3 = 0.f;                      \
            _Pragma("unroll")                                                  \
            for (int q = 0; q < 5; q++) {                                      \
                int base = q * 800;                                            \
                s0 += gbuf[base + (0 * 2 + ub) * 100 + uj];                    \
                s1 += gbuf[base + (1 * 2 + ub) * 100 + uj];                    \
                s2 += gbuf[base + (2 * 2 + ub) * 100 + uj];                    \
                s3 += gbuf[base + (3 * 2 + ub) * 100 + uj];                    \
            }                                                                  \
            float xi = s0 + pb[ub * 400 + uj];                                 \
            float xf = s1 + pb[ub * 400 + 100 + uj];                           \
            float xg = s2 + pb[ub * 400 + 200 + uj];                           \
            float xo = s3 + pb[ub * 400 + 300 + uj];                           \
            float ii = sig_(xi), ff = sig_(xf), gg = th_(xg), oo = sig_(xo);   \
            c = ff * c + ii * gg;                                              \
            float h = oo * th_(c);                                             \
            hs[ub][uj] = h;                                                    \
            hseq[((size_t)(T_) * BT + b0 + ub) * 100 + uj] = h;                \
            ((float4*)(PNXT))[tid] = pf0;                                      \
        }                                                                      \
        __syncthreads();                                                       \
    }

    for (int t = 0; t < Tc; t += 2) {        // Tc is a power of two (even)
        REC1_BODY(t,     pres[0], pres[1]);
        REC1_BODY(t + 1, pres[1], pres[0]);
    }
#undef REC1_BODY
    if (upd) cst[(size_t)(b0 + ub) * 100 + uj] = c;
}

// ---------------------------------------------------------------------------
// rec2 v6: same treatment (no pin, unroll x2, mul-init).
// ---------------------------------------------------------------------------
__global__ __launch_bounds__(256, 4) void rec2(
    const float* __restrict__ pre2,  // [Tc][1024][200]
    const float* __restrict__ Whh,   // [200][50]
    float* __restrict__ cst, float* __restrict__ hst,  // [1024][50]
    float* __restrict__ out,         // [1024][50]
    int Tc, int first)
{
    __shared__ __align__(16) float hs[2][50];
    __shared__ __align__(16) float pres[2][400];
    __shared__ float gbuf[5 * 4 * 2 * 50];
    const int tid = threadIdx.x;
    const int b0 = blockIdx.x * 2;

    const bool comp = tid < 250;
    const int j  = tid % 50;
    const int kq = tid / 50;

    float2 w[4][5];
    if (comp) {
#pragma unroll
        for (int g = 0; g < 4; g++) {
            const float2* W2 = (const float2*)(Whh + (size_t)(g * 50 + j) * 50);
#pragma unroll
            for (int q = 0; q < 5; q++) w[g][q] = W2[kq * 5 + q];
        }
    }

    const bool upd = tid < 100;
    const int ub = tid / 50, uj = tid % 50;
    float c = 0.f, hlast = 0.f;
    if (upd) {
        float h = 0.f;
        if (!first) {
            h = hst[(size_t)(b0 + ub) * 50 + uj];
            c = cst[(size_t)(b0 + ub) * 50 + uj];
        }
        hs[ub][uj] = h;
        hlast = h;
        ((float4*)pres[0])[tid] = ((const float4*)(pre2 + (size_t)b0 * 200))[tid];
    }
    __syncthreads();

#define REC2_BODY(T_, PCUR, PNXT)                                              \
    {                                                                          \
        int tn = ((T_) + 1 < Tc) ? ((T_) + 1) : (T_);                          \
        float4 pf0;                                                            \
        if (upd)                                                               \
            pf0 = ((const float4*)(pre2 + (size_t)tn * BT * 200 +              \
                                   (size_t)b0 * 200))[tid];                    \
        if (comp) {                                                            \
            float acc[4][2];                                                   \
            const float2* hA = (const float2*)hs[0];                           \
            const float2* hB = (const float2*)hs[1];                           \
            {   /* q = 0: mul-init */                                          \
                int f = kq * 5;                                                \
                float2 v0 = hA[f], v1 = hB[f];                                 \
                _Pragma("unroll")                                              \
                for (int g = 0; g < 4; g++) {                                  \
                    float2 wq = w[g][0];                                       \
                    float a0 = wq.x * v0.x; a0 = fmaf(wq.y, v0.y, a0);         \
                    float a1 = wq.x * v1.x; a1 = fmaf(wq.y, v1.y, a1);         \
                    acc[g][0] = a0; acc[g][1] = a1;                            \
                }                                                              \
            }                                                                  \
            _Pragma("unroll")                                                  \
            for (int q = 1; q < 5; q++) {                                      \
                int f = kq * 5 + q;                                            \
                float2 v0 = hA[f], v1 = hB[f];                                 \
                _Pragma("unroll")                                              \
                for (int g = 0; g < 4; g++) {                                  \
                    float2 wq = w[g][q];                                       \
                    acc[g][0] = fmaf(wq.x, v0.x, acc[g][0]);                   \
                    acc[g][0] = fmaf(wq.y, v0.y, acc[g][0]);                   \
                    acc[g][1] = fmaf(wq.x, v1.x, acc[g][1]);                   \
                    acc[g][1] = fmaf(wq.y, v1.y, acc[g][1]);                   \
                }                                                              \
            }                                                                  \
            _Pragma("unroll")                                                  \
            for (int g = 0; g < 4; g++) {                                      \
                gbuf[((kq * 4 + g) * 2 + 0) * 50 + j] = acc[g][0];             \
                gbuf[((kq * 4 + g) * 2 + 1) * 50 + j] = acc[g][1];             \
            }                                                                  \
        }                                                                      \
        __syncthreads();                                                       \
        if (upd) {                                                             \
            const float* pb = (PCUR);                                          \
            float s0 = 0.f, s1 = 0.f, s2 = 0.f, s3 = 0.f;                      \
            _Pragma("unroll")                                                  \
            for (int q = 0; q < 5; q++) {                                      \
                int base = q * 400;                                            \
                s0 += gbuf[base + (0 * 2 + ub) * 50 + uj];                     \
                s1 += gbuf[base + (1 * 2 + ub) * 50 + uj];                     \
                s2 += gbuf[base + (2 * 2 + ub) * 50 + uj];                     \
                s3 += gbuf[base + (3 * 2 + ub) * 50 + uj];                     \
            }                                                                  \
            float xi = s0 + pb[ub * 200 + uj];                                 \
            float xf = s1 + pb[ub * 200 + 50 + uj];                            \
            float xg = s2 + pb[ub * 200 + 100 + uj];                           \
            float xo = s3 + pb[ub * 200 + 150 + uj];                           \
            float ii = sig_(xi), ff = sig_(xf), gg = th_(xg), oo = sig_(xo);   \
            c = ff * c + ii * gg;                                              \
            float h = oo * th_(c);                                             \
            hs[ub][uj] = h;                                                    \
            hlast = h;                                                         \
            ((float4*)(PNXT))[tid] = pf0;                                      \
        }                                                                      \
        __syncthreads();                                                       \
    }

    for (int t = 0; t < Tc; t += 2) {
        REC2_BODY(t,     pres[0], pres[1]);
        REC2_BODY(t + 1, pres[1], pres[0]);
    }
#undef REC2_BODY
    if (upd) {
        cst[(size_t)(b0 + ub) * 50 + uj] = c;
        hst[(size_t)(b0 + ub) * 50 + uj] = hlast;
        out[(size_t)(b0 + ub) * 50 + uj] = hlast;
    }
}

// ---------------------------------------------------------------------------
extern "C" void kernel_launch(void* const* d_in, const int* in_sizes, int n_in,
                              void* d_out, int out_size, void* d_ws, size_t ws_size,
                              hipStream_t stream)
{
    const float* x    = (const float*)d_in[0];
    const float* Wih1 = (const float*)d_in[1];
    const float* Whh1 = (const float*)d_in[2];
    const float* bih1 = (const float*)d_in[3];
    const float* bhh1 = (const float*)d_in[4];
    const float* Wih2 = (const float*)d_in[5];
    const float* Whh2 = (const float*)d_in[6];
    const float* bih2 = (const float*)d_in[7];
    const float* bhh2 = (const float*)d_in[8];
    float* out = (float*)d_out;
    float* ws  = (float*)d_ws;

    int Tc = 64;
    auto need = [](int tc) -> size_t {
        return ((size_t)tc * 1024 * (400 + 100 + 200) +
                (size_t)1024 * 100 + (size_t)1024 * 50 * 2) * sizeof(float);
    };
    while (Tc > 1 && need(Tc) > ws_size) Tc >>= 1;

    float* pre1 = ws;
    float* h1s  = pre1 + (size_t)Tc * 1024 * 400;
    float* pre2 = h1s  + (size_t)Tc * 1024 * 100;
    float* c1   = pre2 + (size_t)Tc * 1024 * 200;
    float* c2   = c1 + 1024 * 100;
    float* h2st = c2 + 1024 * 50;

    const int nch = TT / Tc;
    for (int ch = 0; ch < nch; ch++) {
        int t0 = ch * Tc;
        // K=80: halves 40+40, 128-col blocks: grid (ceil(400/128)=4, Tc*8)
        gemm_pre<80, 40, 40, 400, true ><<<dim3(4, Tc * 8), 256, 0, stream>>>(
            x, Wih1, bih1, bhh1, pre1, t0);
        rec1<<<dim3(512), dim3(512), 0, stream>>>(pre1, Whh1, h1s, c1, Tc, ch == 0 ? 1 : 0);
        // K=100: halves 52+48, 128-col blocks: grid (2, Tc*8)
        gemm_pre<100, 52, 52, 200, false><<<dim3(2, Tc * 8), 256, 0, stream>>>(
            h1s, Wih2, bih2, bhh2, pre2, 0);
        rec2<<<dim3(512), dim3(256), 0, stream>>>(pre2, Whh2, c2, h2st, out, Tc, ch == 0 ? 1 : 0);
    }
}